// Round 11
// baseline (135.776 us; speedup 1.0000x reference)
//
#include <hip/hip_runtime.h>
#include <math.h>

#define DIM 2048          // INPUT_DIM
#define NF 2048           // N_FORMULAS
#define LPF 16            // LITERALS_PER_FORMULA
#define LTOT (NF * LPF)   // 32768
#define BETA 0.4f
#define EPS 1.0f
#define NDCH 64           // d-chunks for the reduction
#define DCH (DIM / NDCH)  // 32 rows per chunk

typedef float f32x4 __attribute__((ext_vector_type(4)));
typedef unsigned long long u64;

// ---------------------------------------------------------------------------
// Kernel A: per-formula partial reduction + bit-pack of both masks.
// grid (NF/256, NDCH) = (8,64), block 256. Lanes hold consecutive f for a
// fixed d -> __ballot packs 64 formulas/u64. pack_*[d][w] w=0..31.
// ws: [NDCH][3][NF] partials | ws2[NF] | pack_lm[2048*32 u64] | pack_fr[...]
// ---------------------------------------------------------------------------
__global__ void reduce_pack(const float* __restrict__ lm,
                            const float* __restrict__ frm,
                            float* __restrict__ ws,
                            u64* __restrict__ pack_lm,
                            u64* __restrict__ pack_fr) {
    const int t = threadIdx.x;
    const int f = blockIdx.x * 256 + t;              // formula column
    const int d0 = blockIdx.y * DCH;
    const int wv = t >> 6;                           // wave id 0..3
    const int lane = t & 63;

    float sq = 0.0f, l1 = 0.0f, cnt = 0.0f;
    #pragma unroll 4
    for (int i = 0; i < DCH; ++i) {
        const int d = d0 + i;
        const size_t off = ((size_t)d << 11) + f;    // row stride 2048
        float x = lm[off];
        float r = frm[off];
        sq  = fmaf(x * x, r, sq);
        l1  = fmaf(fabsf(x), r, l1);
        cnt += r;
        u64 bl = __ballot(fabsf(x) > EPS);           // binarized lm bits
        u64 br = __ballot(r > 0.5f);                 // frm bits (r in {0,1})
        if (lane == 0) {
            const size_t widx = (size_t)d * 32 + blockIdx.x * 4 + wv;
            pack_lm[widx] = bl;
            pack_fr[widx] = br;
        }
    }

    float* w = ws + (size_t)blockIdx.y * 3 * NF;
    w[0 * NF + f] = sq;
    w[1 * NF + f] = l1;
    w[2 * NF + f] = cnt;
}

// ---------------------------------------------------------------------------
// Kernel B: PURE-WRITE expansion. One output row per block; the row's data
// is 32 block-uniform u64 words (256 B) -> scalar-path loads; the vector
// memory pipe issues ONLY stores (fillBuffer's regime). Plain stores to
// test the write-combine path hypothesis (6.7 TB/s).
// grid = 2*DIM = 4096 blocks, 256 threads.
// Thread t, iter i: f = i*64 + (t>>2) -> word i, bit (t>>2).
// ---------------------------------------------------------------------------
__global__ void expand_pure(const u64* __restrict__ pack_lm,
                            const u64* __restrict__ pack_fr,
                            f32x4* __restrict__ out0,
                            f32x4* __restrict__ out1) {
    const int t = threadIdx.x;
    const int bx = blockIdx.x;
    const bool is1 = bx >= DIM;
    const int d = is1 ? bx - DIM : bx;
    const u64* pack = (is1 ? pack_fr : pack_lm) + (size_t)d * 32;
    f32x4* dst = (is1 ? out1 : out0) + ((size_t)d << 13);  // row base, 8192 f4
    const unsigned sh = t >> 2;

    u64 w[32];
    #pragma unroll
    for (int i = 0; i < 32; ++i)
        w[i] = pack[i];                   // block-uniform -> s_load / K$

    #pragma unroll
    for (int i = 0; i < 32; ++i) {
        float v = ((w[i] >> sh) & 1ull) ? 1.0f : 0.0f;
        f32x4 q = { v, v, v, v };
        dst[i * 256 + t] = q;             // plain full-line store burst
    }
}

// ---------------------------------------------------------------------------
// Kernel C: per-formula term from chunk partials. grid = NF/256 blocks.
// ---------------------------------------------------------------------------
__global__ void formula_term_kernel(const float* __restrict__ ws,
                                    const float* __restrict__ alpha,
                                    float* __restrict__ ws2) {
    const int f = blockIdx.x * blockDim.x + threadIdx.x;
    float sig = 1.0f / (1.0f + expf(-alpha[0]));
    float w_l2 = (1.0f - sig) * 0.5f;
    float w_l1 = sig;

    float sq = 0.0f, l1 = 0.0f, cnt = 0.0f;
    for (int c = 0; c < NDCH; ++c) {
        const float* w = ws + (size_t)c * 3 * NF;
        sq  += w[0 * NF + f];
        l1  += w[1 * NF + f];
        cnt += w[2 * NF + f];
    }
    float l2t = fabsf(sq / cnt - BETA * EPS * EPS);
    float l1t = fabsf(l1 / cnt - BETA * EPS);
    ws2[f] = l2t * w_l2 + l1t * w_l1;
}

// ---------------------------------------------------------------------------
// Kernel D: mean over formulas. 1 block, deterministic LDS tree.
// ---------------------------------------------------------------------------
__global__ void final_sum_kernel(const float* __restrict__ ws2,
                                 float* __restrict__ out_scalar) {
    __shared__ float red[256];
    const int t = threadIdx.x;
    float total = 0.0f;
    for (int k = 0; k < NF / 256; ++k)
        total += ws2[t + k * 256];
    red[t] = total;
    __syncthreads();
    for (int s = 128; s > 0; s >>= 1) {
        if (t < s) red[t] += red[t + s];
        __syncthreads();
    }
    if (t == 0) out_scalar[0] = red[0] / (float)NF;
}

extern "C" void kernel_launch(void* const* d_in, const int* in_sizes, int n_in,
                              void* d_out, int out_size, void* d_ws, size_t ws_size,
                              hipStream_t stream) {
    const float* lm    = (const float*)d_in[0];  // learnable_mask [D, F]
    const float* alpha = (const float*)d_in[1];  // elastic_net_alpha [1]
    const float* frm   = (const float*)d_in[2];  // formulas_random_mask [D, F]
    // d_in[3] = formula_id_per_literal (implicit: l // 16)

    float* out = (float*)d_out;
    float* ws  = (float*)d_ws;

    const size_t big = (size_t)DIM * LTOT;       // 67,108,864 per output
    f32x4* out0 = (f32x4*)out;                   // learnable_binary_mask
    f32x4* out1 = (f32x4*)(out + big);           // literals_random_mask
    float* out_scalar = out + 2 * big;           // elastic_net_reg

    // ws layout (floats): partials [NDCH*3*NF] | ws2 [NF] | packed bits
    float* ws2 = ws + (size_t)NDCH * 3 * NF;
    u64* pack_lm = (u64*)(ws2 + NF);             // offset 1,585,152 B (8B-aligned)
    u64* pack_fr = pack_lm + (size_t)DIM * 32;   // +512 KB
    // total ws use: 1.58 MB + 1.0 MB = 2.6 MB

    // A: reduction partials + bit-pack (reads phase)
    dim3 gridA(NF / 256, NDCH);
    reduce_pack<<<gridA, 256, 0, stream>>>(lm, frm, ws, pack_lm, pack_fr);

    // B: pure-write expansion from packed bits (plain stores, no vector loads)
    expand_pure<<<2 * DIM, 256, 0, stream>>>(pack_lm, pack_fr, out0, out1);

    // C/D: tiny epilogues
    formula_term_kernel<<<NF / 256, 256, 0, stream>>>(ws, alpha, ws2);
    final_sum_kernel<<<1, 256, 0, stream>>>(ws2, out_scalar);
}

// Round 12
// 129.366 us; speedup vs baseline: 1.0495x; 1.0495x over previous
//
#include <hip/hip_runtime.h>
#include <math.h>

#define DIM 2048          // INPUT_DIM
#define NF 2048           // N_FORMULAS
#define LPF 16            // LITERALS_PER_FORMULA
#define LTOT (NF * LPF)   // 32768
#define BETA 0.4f
#define EPS 1.0f
#define NDCH 64           // d-chunks for the reduction
#define DCH (DIM / NDCH)  // 32 rows per chunk

typedef float f32x4 __attribute__((ext_vector_type(4)));
typedef unsigned long long u64;

// ---------------------------------------------------------------------------
// Kernel A: per-formula partial reduction + bit-pack of both masks.
// grid (NF/256, NDCH) = (8,64), block 256. Lanes hold consecutive f for a
// fixed d -> __ballot packs 64 formulas/u64. pack_*[d][w] w=0..31.
// ws: [NDCH][3][NF] partials | ws2[NF] | pack_lm[2048*32 u64] | pack_fr[...]
// ---------------------------------------------------------------------------
__global__ void reduce_pack(const float* __restrict__ lm,
                            const float* __restrict__ frm,
                            float* __restrict__ ws,
                            u64* __restrict__ pack_lm,
                            u64* __restrict__ pack_fr) {
    const int t = threadIdx.x;
    const int f = blockIdx.x * 256 + t;              // formula column
    const int d0 = blockIdx.y * DCH;
    const int wv = t >> 6;                           // wave id 0..3
    const int lane = t & 63;

    float sq = 0.0f, l1 = 0.0f, cnt = 0.0f;
    #pragma unroll 4
    for (int i = 0; i < DCH; ++i) {
        const int d = d0 + i;
        const size_t off = ((size_t)d << 11) + f;    // row stride 2048
        float x = lm[off];
        float r = frm[off];
        sq  = fmaf(x * x, r, sq);
        l1  = fmaf(fabsf(x), r, l1);
        cnt += r;
        u64 bl = __ballot(fabsf(x) > EPS);           // binarized lm bits
        u64 br = __ballot(r > 0.5f);                 // frm bits (r in {0,1})
        if (lane == 0) {
            const size_t widx = (size_t)d * 32 + blockIdx.x * 4 + wv;
            pack_lm[widx] = bl;
            pack_fr[widx] = br;
        }
    }

    float* w = ws + (size_t)blockIdx.y * 3 * NF;
    w[0 * NF + f] = sq;
    w[1 * NF + f] = l1;
    w[2 * NF + f] = cnt;
}

// ---------------------------------------------------------------------------
// Kernel B: PURE-WRITE expansion, NT stores (R12: single change vs R11).
// One output row per block; row data is 32 block-uniform u64 words (256 B)
// via the scalar path -> the vector memory pipe issues ONLY the nt store
// burst. grid = 2*DIM = 4096 blocks, 256 threads.
// Thread t, iter i: f = i*64 + (t>>2) -> word i, bit (t>>2).
// ---------------------------------------------------------------------------
__global__ void expand_pure(const u64* __restrict__ pack_lm,
                            const u64* __restrict__ pack_fr,
                            f32x4* __restrict__ out0,
                            f32x4* __restrict__ out1) {
    const int t = threadIdx.x;
    const int bx = blockIdx.x;
    const bool is1 = bx >= DIM;
    const int d = is1 ? bx - DIM : bx;
    const u64* pack = (is1 ? pack_fr : pack_lm) + (size_t)d * 32;
    f32x4* dst = (is1 ? out1 : out0) + ((size_t)d << 13);  // row base, 8192 f4
    const unsigned sh = t >> 2;

    u64 w[32];
    #pragma unroll
    for (int i = 0; i < 32; ++i)
        w[i] = pack[i];                   // block-uniform -> s_load / K$

    #pragma unroll
    for (int i = 0; i < 32; ++i) {
        float v = ((w[i] >> sh) & 1ull) ? 1.0f : 0.0f;
        f32x4 q = { v, v, v, v };
        __builtin_nontemporal_store(q, &dst[i * 256 + t]);
    }
}

// ---------------------------------------------------------------------------
// Kernel C: per-formula term from chunk partials. grid = NF/256 blocks.
// ---------------------------------------------------------------------------
__global__ void formula_term_kernel(const float* __restrict__ ws,
                                    const float* __restrict__ alpha,
                                    float* __restrict__ ws2) {
    const int f = blockIdx.x * blockDim.x + threadIdx.x;
    float sig = 1.0f / (1.0f + expf(-alpha[0]));
    float w_l2 = (1.0f - sig) * 0.5f;
    float w_l1 = sig;

    float sq = 0.0f, l1 = 0.0f, cnt = 0.0f;
    for (int c = 0; c < NDCH; ++c) {
        const float* w = ws + (size_t)c * 3 * NF;
        sq  += w[0 * NF + f];
        l1  += w[1 * NF + f];
        cnt += w[2 * NF + f];
    }
    float l2t = fabsf(sq / cnt - BETA * EPS * EPS);
    float l1t = fabsf(l1 / cnt - BETA * EPS);
    ws2[f] = l2t * w_l2 + l1t * w_l1;
}

// ---------------------------------------------------------------------------
// Kernel D: mean over formulas. 1 block, deterministic LDS tree.
// ---------------------------------------------------------------------------
__global__ void final_sum_kernel(const float* __restrict__ ws2,
                                 float* __restrict__ out_scalar) {
    __shared__ float red[256];
    const int t = threadIdx.x;
    float total = 0.0f;
    for (int k = 0; k < NF / 256; ++k)
        total += ws2[t + k * 256];
    red[t] = total;
    __syncthreads();
    for (int s = 128; s > 0; s >>= 1) {
        if (t < s) red[t] += red[t + s];
        __syncthreads();
    }
    if (t == 0) out_scalar[0] = red[0] / (float)NF;
}

extern "C" void kernel_launch(void* const* d_in, const int* in_sizes, int n_in,
                              void* d_out, int out_size, void* d_ws, size_t ws_size,
                              hipStream_t stream) {
    const float* lm    = (const float*)d_in[0];  // learnable_mask [D, F]
    const float* alpha = (const float*)d_in[1];  // elastic_net_alpha [1]
    const float* frm   = (const float*)d_in[2];  // formulas_random_mask [D, F]
    // d_in[3] = formula_id_per_literal (implicit: l // 16)

    float* out = (float*)d_out;
    float* ws  = (float*)d_ws;

    const size_t big = (size_t)DIM * LTOT;       // 67,108,864 per output
    f32x4* out0 = (f32x4*)out;                   // learnable_binary_mask
    f32x4* out1 = (f32x4*)(out + big);           // literals_random_mask
    float* out_scalar = out + 2 * big;           // elastic_net_reg

    // ws layout (floats): partials [NDCH*3*NF] | ws2 [NF] | packed bits
    float* ws2 = ws + (size_t)NDCH * 3 * NF;
    u64* pack_lm = (u64*)(ws2 + NF);             // 8B-aligned
    u64* pack_fr = pack_lm + (size_t)DIM * 32;   // +512 KB
    // total ws use: 1.58 MB + 1.0 MB = 2.6 MB

    // A: reduction partials + bit-pack (reads phase)
    dim3 gridA(NF / 256, NDCH);
    reduce_pack<<<gridA, 256, 0, stream>>>(lm, frm, ws, pack_lm, pack_fr);

    // B: pure-write nt expansion from packed bits
    expand_pure<<<2 * DIM, 256, 0, stream>>>(pack_lm, pack_fr, out0, out1);

    // C/D: tiny epilogues
    formula_term_kernel<<<NF / 256, 256, 0, stream>>>(ws, alpha, ws2);
    final_sum_kernel<<<1, 256, 0, stream>>>(ws2, out_scalar);
}

// Round 13
// 116.138 us; speedup vs baseline: 1.1691x; 1.1139x over previous
//
#include <hip/hip_runtime.h>
#include <math.h>

#define DIM 2048          // INPUT_DIM
#define NF 2048           // N_FORMULAS
#define LPF 16            // LITERALS_PER_FORMULA
#define LTOT (NF * LPF)   // 32768
#define BETA 0.4f
#define EPS 1.0f
#define NDCH 64           // d-chunks for the reduction
#define DCH (DIM / NDCH)  // 32 rows per chunk

typedef float f32x4 __attribute__((ext_vector_type(4)));

// ---------------------------------------------------------------------------
// Kernel A: per-formula partial reduction + LLC prefetch of both inputs.
// grid (NF/256, NDCH) = 512 blocks. Scalar but fully-coalesced loads.
// ws layout: [NDCH][3][NF] floats, then ws2[NF].  (unchanged from R9)
// ---------------------------------------------------------------------------
__global__ void reduce_prefetch(const float* __restrict__ lm,
                                const float* __restrict__ frm,
                                float* __restrict__ ws) {
    const int f = blockIdx.x * 256 + threadIdx.x;    // formula column
    const int d0 = blockIdx.y * DCH;

    float sq = 0.0f, l1 = 0.0f, cnt = 0.0f;
    #pragma unroll 8
    for (int i = 0; i < DCH; ++i) {
        const size_t off = ((size_t)(d0 + i) << 11) + f;   // row stride 2048
        float x = lm[off];
        float r = frm[off];
        sq  = fmaf(x * x, r, sq);
        l1  = fmaf(fabsf(x), r, l1);
        cnt += r;
    }

    float* w = ws + (size_t)blockIdx.y * 3 * NF;
    w[0 * NF + f] = sq;
    w[1 * NF + f] = l1;
    w[2 * NF + f] = cnt;
}

// ---------------------------------------------------------------------------
// Kernel B: expansion, nt stores, FILL-LIKE CONCURRENCY (R13 change vs R9:
// grid 4096 -> 512 blocks; 2 blocks/CU like fillBuffer's ~10% occupancy).
// Each block streams 8 consecutive rows of ONE output array; next row's 32
// values are preloaded while the current row's 32-store nt burst issues
// (loads are oldest in the vmcnt queue, so waiting on them never requires
// draining the posted stores). Per-CU concurrent store streams: 32 -> 8.
// ---------------------------------------------------------------------------
__global__ void expand_stream(const float* __restrict__ lm,
                              const float* __restrict__ frm,
                              f32x4* __restrict__ out0,
                              f32x4* __restrict__ out1) {
    const int t = threadIdx.x;
    const int bx = blockIdx.x;                   // 0..511
    const bool is1 = bx >= 256;
    const int base = (is1 ? bx - 256 : bx) * 8;  // first of 8 rows
    const float* src = is1 ? frm : lm;
    f32x4* outb = is1 ? out1 : out0;

    float cur[32], nxt[32];
    const float* row0 = src + ((size_t)base << 11) + (t >> 2);
    #pragma unroll
    for (int i = 0; i < 32; ++i)
        cur[i] = row0[i * 64];                   // 4-lane broadcast segments

    for (int rr = 0; rr < 8; ++rr) {
        const int d = base + rr;
        if (rr < 7) {                            // prefetch next row
            const float* rown = src + ((size_t)(d + 1) << 11) + (t >> 2);
            #pragma unroll
            for (int i = 0; i < 32; ++i)
                nxt[i] = rown[i * 64];
        }
        if (!is1) {
            #pragma unroll
            for (int i = 0; i < 32; ++i)
                cur[i] = (fabsf(cur[i]) > EPS) ? 1.0f : 0.0f;
        }
        f32x4* dst = outb + ((size_t)d << 13);   // row base, 8192 f4
        #pragma unroll
        for (int i = 0; i < 32; ++i) {
            f32x4 q = { cur[i], cur[i], cur[i], cur[i] };
            __builtin_nontemporal_store(q, &dst[i * 256 + t]);
        }
        #pragma unroll
        for (int i = 0; i < 32; ++i)
            cur[i] = nxt[i];
    }
}

// ---------------------------------------------------------------------------
// Kernel C: per-formula term from chunk partials. grid = NF/256 blocks.
// ---------------------------------------------------------------------------
__global__ void formula_term_kernel(const float* __restrict__ ws,
                                    const float* __restrict__ alpha,
                                    float* __restrict__ ws2) {
    const int f = blockIdx.x * blockDim.x + threadIdx.x;
    float sig = 1.0f / (1.0f + expf(-alpha[0]));
    float w_l2 = (1.0f - sig) * 0.5f;
    float w_l1 = sig;

    float sq = 0.0f, l1 = 0.0f, cnt = 0.0f;
    for (int c = 0; c < NDCH; ++c) {
        const float* w = ws + (size_t)c * 3 * NF;
        sq  += w[0 * NF + f];
        l1  += w[1 * NF + f];
        cnt += w[2 * NF + f];
    }
    float l2t = fabsf(sq / cnt - BETA * EPS * EPS);
    float l1t = fabsf(l1 / cnt - BETA * EPS);
    ws2[f] = l2t * w_l2 + l1t * w_l1;
}

// ---------------------------------------------------------------------------
// Kernel D: mean over formulas. 1 block, deterministic LDS tree.
// ---------------------------------------------------------------------------
__global__ void final_sum_kernel(const float* __restrict__ ws2,
                                 float* __restrict__ out_scalar) {
    __shared__ float red[256];
    const int t = threadIdx.x;
    float total = 0.0f;
    for (int k = 0; k < NF / 256; ++k)
        total += ws2[t + k * 256];
    red[t] = total;
    __syncthreads();
    for (int s = 128; s > 0; s >>= 1) {
        if (t < s) red[t] += red[t + s];
        __syncthreads();
    }
    if (t == 0) out_scalar[0] = red[0] / (float)NF;
}

extern "C" void kernel_launch(void* const* d_in, const int* in_sizes, int n_in,
                              void* d_out, int out_size, void* d_ws, size_t ws_size,
                              hipStream_t stream) {
    const float* lm    = (const float*)d_in[0];  // learnable_mask [D, F]
    const float* alpha = (const float*)d_in[1];  // elastic_net_alpha [1]
    const float* frm   = (const float*)d_in[2];  // formulas_random_mask [D, F]
    // d_in[3] = formula_id_per_literal (implicit: l // 16)

    float* out = (float*)d_out;
    float* ws  = (float*)d_ws;   // needs (NDCH*3*NF + NF)*4 = 1.58 MB

    const size_t big = (size_t)DIM * LTOT;       // 67,108,864 per output
    f32x4* out0 = (f32x4*)out;                   // learnable_binary_mask
    f32x4* out1 = (f32x4*)(out + big);           // literals_random_mask
    float* out_scalar = out + 2 * big;           // elastic_net_reg
    float* ws2 = ws + (size_t)NDCH * 3 * NF;

    // A: reduction partials + LLC prefetch of both inputs (reads phase)
    dim3 gridA(NF / 256, NDCH);
    reduce_prefetch<<<gridA, 256, 0, stream>>>(lm, frm, ws);

    // B: nt expansion, fill-like concurrency (512 blocks, 8 rows each)
    expand_stream<<<512, 256, 0, stream>>>(lm, frm, out0, out1);

    // C/D: tiny epilogues
    formula_term_kernel<<<NF / 256, 256, 0, stream>>>(ws, alpha, ws2);
    final_sum_kernel<<<1, 256, 0, stream>>>(ws2, out_scalar);
}